// Round 10
// baseline (592.830 us; speedup 1.0000x reference)
//
#include <hip/hip_runtime.h>
#include <hip/hip_fp16.h>

#define Nn 50000
#define Ee 800000
#define HD 128        // D == H == 128
#define Ll 3
#define Gg 128
#define Cc 10
#define BN_EPS 1e-5f
#define NBLK1 782     // ceil(Nn/64) — gemm row-tiles
#define NPART 1564    // NBLK1*2 — BN partial slots (per row-half)
#define PPAD 1600     // padded partial stride (feature-major layout)
#define NSCB 49       // ceil(Nn/1024) — scan blocks

typedef __attribute__((ext_vector_type(8))) __bf16 bf16x8;
typedef __attribute__((ext_vector_type(4))) __bf16 bf16x4;
typedef __attribute__((ext_vector_type(2))) __bf16 bf16x2;
typedef __attribute__((ext_vector_type(4))) float f32x4;

// ----------------------------- CSR build ------------------------------------
__global__ void k_deg(const int* __restrict__ dst, int* __restrict__ deg) {
  int i = blockIdx.x * blockDim.x + threadIdx.x;
  int base = i * 4;
  if (base >= Ee) return;
#pragma unroll
  for (int j = 0; j < 4; ++j) {
    int e = base + j;
    if (e < Ee) atomicAdd(&deg[dst[e]], 1);
  }
}

__global__ void k_scan1(const int* __restrict__ deg, int* __restrict__ offs,
                        int* __restrict__ bsum) {
  __shared__ int b0[1024], b1[1024];
  int tid = threadIdx.x;
  int i = blockIdx.x * 1024 + tid;
  int v = (i < Nn) ? deg[i] : 0;
  int* cur = b0; int* nxt = b1;
  cur[tid] = v;
  __syncthreads();
  for (int off = 1; off < 1024; off <<= 1) {
    int s = cur[tid] + ((tid >= off) ? cur[tid - off] : 0);
    nxt[tid] = s;
    __syncthreads();
    int* t = cur; cur = nxt; nxt = t;
  }
  if (i < Nn) offs[i] = cur[tid] - v;          // exclusive within block
  if (tid == 1023) bsum[blockIdx.x] = cur[1023];
}

__global__ void k_scan2(const int* __restrict__ bsum, int* __restrict__ carry) {
  int lane = threadIdx.x;                      // 64 threads, one wave
  int v = (lane < NSCB) ? bsum[lane] : 0;
  int s = v;
  for (int off = 1; off < 64; off <<= 1) {
    int t = __shfl_up(s, off, 64);
    if (lane >= off) s += t;
  }
  if (lane < NSCB) carry[lane] = s - v;        // exclusive carry per block
}

__global__ void k_scan3(const int* __restrict__ carry, int* __restrict__ offs,
                        int* __restrict__ cursor) {
  int i = blockIdx.x * 1024 + threadIdx.x;
  if (i < Nn) {
    int o = offs[i] + carry[blockIdx.x];
    offs[i] = o; cursor[i] = o;
  }
  if (i == 0) offs[Nn] = Ee;
}

// packed edge fill: (src:16 | fp16 weight:16) = 4B/edge, 4 chains in flight.
// plain stores (nt probe regressed: line-migration-bound, nt blocked merging).
__global__ void k_fill(const int* __restrict__ src, const int* __restrict__ dst,
                       const float* __restrict__ ec, int* __restrict__ cursor,
                       unsigned int* __restrict__ epk) {
  int i = blockIdx.x * blockDim.x + threadIdx.x;
  int base = i * 4;
  if (base >= Ee) return;
  int d[4], s[4], p[4]; unsigned short hb[4]; bool ok[4];
#pragma unroll
  for (int j = 0; j < 4; ++j) {
    int e = base + j;
    ok[j] = e < Ee;
    if (ok[j]) {
      d[j] = dst[e]; s[j] = src[e];
      hb[j] = __half_as_ushort(__float2half(ec[e]));
    }
  }
#pragma unroll
  for (int j = 0; j < 4; ++j)
    if (ok[j]) p[j] = atomicAdd(&cursor[d[j]], 1);
#pragma unroll
  for (int j = 0; j < 4; ++j)
    if (ok[j]) epk[p[j]] = ((unsigned int)s[j] << 16) | hb[j];
}

// ---- x -> bf16 copy (layer-0 activation stream) ----------------------------
__global__ void k_xcast(const float* __restrict__ x, __bf16* __restrict__ xb) {
  int i = blockIdx.x * blockDim.x + threadIdx.x;
  int stride = gridDim.x * blockDim.x;
  const int n4 = Nn * 32;                      // Nn*128/4
  for (int t = i; t < n4; t += stride) {
    f32x4 v = ((const f32x4*)x)[t];
    bf16x4 b;
#pragma unroll
    for (int j = 0; j < 4; ++j) b[j] = (__bf16)v[j];
    ((bf16x4*)xb)[t] = b;
  }
}

// ---- W prep: Wt_hi/lo[n][k] bf16 split of W[k][n], 6 matrices (3xW1,3xW2) --
__global__ void k_wprep(const float* __restrict__ W1, const float* __restrict__ W2,
                        __bf16* __restrict__ wtHi, __bf16* __restrict__ wtLo) {
  int mat = blockIdx.x >> 3;                    // 0..5
  int chunk = blockIdx.x & 7;                   // 0..7 (2048 elems each)
  const float* W = (mat < 3) ? (W1 + mat * 16384) : (W2 + (mat - 3) * 16384);
  __bf16* hi = wtHi + mat * 16384;
  __bf16* lo = wtLo + mat * 16384;
  for (int t = threadIdx.x; t < 2048; t += blockDim.x) {
    int idx = chunk * 2048 + t;                 // Wt index: n*128 + k
    int n = idx >> 7, k = idx & 127;
    float v = W[k * 128 + n];
    __bf16 h = (__bf16)v;
    hi[idx] = h;
    lo[idx] = (__bf16)(v - (float)h);
  }
}

// ---- GEMM1 (fused gather + MFMA, 4 waves, 64-row tile) ---------------------
// Phase 1: each wave gathers 16 rows (8-edge ILP, fp32 acc), A = agg*nc + x,
//          bf16-pack into XOR-swizzled LDS (conflict-free store & b128 read).
// Phase 2: 4 waves x (32x64) MFMA tiles; A single-bf16, W hi/lo (2 MFMA/tile).
// Epilogue: bias, bf16 h1 store, BN column partials.
__launch_bounds__(256)
__global__ void k_gemm1(const __bf16* __restrict__ xb, const float* __restrict__ nc,
                        const int* __restrict__ offs, const unsigned int* __restrict__ epk,
                        const __bf16* __restrict__ wtHi, const __bf16* __restrict__ wtLo,
                        const float* __restrict__ bias, __bf16* __restrict__ h1b,
                        float* __restrict__ partial) {
  __shared__ unsigned int Als[64 * 64];        // 16 KB: [row][swizzled 64 uints]
  int tid = threadIdx.x;
  int w = tid >> 6, l = tid & 63;
  int row0 = blockIdx.x * 64;
  const unsigned int* x2 = (const unsigned int*)xb;

  // ---------------- phase 1: gather rows row0 + w*16 .. +15 -----------------
  for (int it = 0; it < 16; ++it) {
    int n = row0 + w * 16 + it;
    float sx = 0.f, sy = 0.f;
    if (n < Nn) {
      int beg = offs[n], end = offs[n + 1];
      float ax[8], ay[8];
#pragma unroll
      for (int t = 0; t < 8; ++t) { ax[t] = 0.f; ay[t] = 0.f; }
      int j = beg;
      for (; j + 7 < end; j += 8) {
        unsigned int e[8], v[8];
#pragma unroll
        for (int t = 0; t < 8; ++t) e[t] = epk[j + t];
#pragma unroll
        for (int t = 0; t < 8; ++t) v[t] = x2[(e[t] >> 16) * 64 + l];
#pragma unroll
        for (int t = 0; t < 8; ++t) {
          __half_raw h; h.x = (unsigned short)(e[t] & 0xffffu);
          float wv = __half2float(h);
          ax[t] = fmaf(__uint_as_float(v[t] << 16), wv, ax[t]);
          ay[t] = fmaf(__uint_as_float(v[t] & 0xffff0000u), wv, ay[t]);
        }
      }
      for (; j < end; ++j) {
        unsigned int e = epk[j];
        unsigned int v = x2[(e >> 16) * 64 + l];
        __half_raw h; h.x = (unsigned short)(e & 0xffffu);
        float wv = __half2float(h);
        ax[0] = fmaf(__uint_as_float(v << 16), wv, ax[0]);
        ay[0] = fmaf(__uint_as_float(v & 0xffff0000u), wv, ay[0]);
      }
      float gx = (ax[0] + ax[1]) + (ax[2] + ax[3]) + ((ax[4] + ax[5]) + (ax[6] + ax[7]));
      float gy = (ay[0] + ay[1]) + (ay[2] + ay[3]) + ((ay[4] + ay[5]) + (ay[6] + ay[7]));
      float ncv = nc[n];
      unsigned int xv = x2[n * 64 + l];
      sx = fmaf(gx, ncv, __uint_as_float(xv << 16));
      sy = fmaf(gy, ncv, __uint_as_float(xv & 0xffff0000u));
    }
    bf16x2 tpk; tpk[0] = (__bf16)sx; tpk[1] = (__bf16)sy;
    unsigned int o = *(unsigned int*)&tpk;
    // swizzle: slot16 = col16 ^ (row&15); row&15 == it here
    int sw = (((l >> 2) ^ it) << 2) | (l & 3);
    Als[(w * 16 + it) * 64 + sw] = o;
  }
  __syncthreads();

  // ---------------- phase 2: MFMA -------------------------------------------
  int wr = w >> 1, wc = w & 1;
  int l15 = l & 15, lg = l >> 4;
  int colw = wc * 64;

  f32x4 acc[2][4];
#pragma unroll
  for (int m = 0; m < 2; ++m)
#pragma unroll
    for (int n = 0; n < 4; ++n) acc[m][n] = (f32x4){0.f, 0.f, 0.f, 0.f};

#pragma unroll
  for (int ks = 0; ks < 4; ++ks) {
    int k0 = ks * 32 + lg * 8;
    bf16x8 a[2];
#pragma unroll
    for (int m = 0; m < 2; ++m) {
      int lr = wr * 32 + m * 16 + l15;
      int slot = (((ks * 4 + lg) ^ l15) << 2);
      a[m] = *(const bf16x8*)&Als[lr * 64 + slot];
    }
    bf16x8 bHi[4], bLo[4];
#pragma unroll
    for (int n = 0; n < 4; ++n) {
      int c = colw + n * 16 + l15;
      bHi[n] = *(const bf16x8*)(wtHi + c * 128 + k0);
      bLo[n] = *(const bf16x8*)(wtLo + c * 128 + k0);
    }
#pragma unroll
    for (int m = 0; m < 2; ++m)
#pragma unroll
      for (int n = 0; n < 4; ++n) {
        acc[m][n] = __builtin_amdgcn_mfma_f32_16x16x32_bf16(a[m], bHi[n], acc[m][n], 0, 0, 0);
        acc[m][n] = __builtin_amdgcn_mfma_f32_16x16x32_bf16(a[m], bLo[n], acc[m][n], 0, 0, 0);
      }
  }

  // epilogue: bias, bf16 store, BN column stats (fp32, pre-rounding)
  int row0w = row0 + wr * 32;
  float s[4] = {0.f, 0.f, 0.f, 0.f}, q[4] = {0.f, 0.f, 0.f, 0.f};
#pragma unroll
  for (int n = 0; n < 4; ++n) {
    int c = colw + n * 16 + l15;
    float bv = bias[c];
#pragma unroll
    for (int m = 0; m < 2; ++m) {
      int rbase = row0w + m * 16 + lg * 4;
#pragma unroll
      for (int r = 0; r < 4; ++r) {
        int rr = rbase + r;
        if (rr < Nn) {
          float o = acc[m][n][r] + bv;
          h1b[rr * 128 + c] = (__bf16)o;
          s[n] += o; q[n] += o * o;
        }
      }
    }
  }
#pragma unroll
  for (int n = 0; n < 4; ++n) {
    s[n] += __shfl_xor(s[n], 16, 64); q[n] += __shfl_xor(q[n], 16, 64);
    s[n] += __shfl_xor(s[n], 32, 64); q[n] += __shfl_xor(q[n], 32, 64);
  }
  if (lg == 0) {
    int slot = blockIdx.x * 2 + wr;
#pragma unroll
    for (int n = 0; n < 4; ++n) {
      int f = colw + n * 16 + l15;
      partial[f * PPAD + slot] = s[n];
      partial[(128 + f) * PPAD + slot] = q[n];
    }
  }
}

// parallel partial reduce: one block per feature, coalesced strided reads.
__global__ void k_bnfin(const float* __restrict__ partial,
                        const float* __restrict__ g1, const float* __restrict__ be1,
                        float* __restrict__ scaleA, float* __restrict__ shiftA) {
  __shared__ float ss[256], qq[256];
  int f = blockIdx.x, t = threadIdx.x;
  float s = 0.f, q = 0.f;
  for (int b = t; b < NPART; b += 256) {
    s += partial[f * PPAD + b];
    q += partial[(128 + f) * PPAD + b];
  }
  ss[t] = s; qq[t] = q;
  __syncthreads();
  for (int off = 128; off > 0; off >>= 1) {
    if (t < off) { ss[t] += ss[t + off]; qq[t] += qq[t + off]; }
    __syncthreads();
  }
  if (t == 0) {
    const float inv = 1.0f / (float)Nn;
    float mu = ss[0] * inv;
    float var = fmaxf(qq[0] * inv - mu * mu, 0.f);
    float rs = rsqrtf(var + BN_EPS);
    float sc = rs * g1[f];
    scaleA[f] = sc;
    shiftA[f] = be1[f] - mu * sc;
  }
}

// ---- GEMM2 (MFMA, 4 waves): xb = bf16(relu( relu(h1b*sc+sh) @ W2 + b2 )) ---
// A single-bf16 round, W hi/lo: 2 MFMA per tile per k-step.
__launch_bounds__(256)
__global__ void k_gemm2(const __bf16* __restrict__ h1b, const float* __restrict__ scaleA,
                        const float* __restrict__ shiftA,
                        const __bf16* __restrict__ wtHi, const __bf16* __restrict__ wtLo,
                        const float* __restrict__ bias, __bf16* __restrict__ xbout) {
  int tid = threadIdx.x;
  int w = tid >> 6, l = tid & 63;
  int wr = w >> 1, wc = w & 1;
  int row0 = blockIdx.x * 64 + wr * 32;
  int l15 = l & 15, lg = l >> 4;
  int colw = wc * 64;
  int krow = lg * 8;

  f32x4 acc[2][4];
#pragma unroll
  for (int m = 0; m < 2; ++m)
#pragma unroll
    for (int n = 0; n < 4; ++n) acc[m][n] = (f32x4){0.f, 0.f, 0.f, 0.f};

  int rowA[2]; bool rv[2];
#pragma unroll
  for (int m = 0; m < 2; ++m) {
    rowA[m] = row0 + m * 16 + l15;
    rv[m] = rowA[m] < Nn;
  }

#pragma unroll
  for (int ks = 0; ks < 4; ++ks) {
    int k0 = ks * 32 + krow;
    f32x4 sc0 = *(const f32x4*)(scaleA + k0), sc1 = *(const f32x4*)(scaleA + k0 + 4);
    f32x4 sh0 = *(const f32x4*)(shiftA + k0), sh1 = *(const f32x4*)(shiftA + k0 + 4);
    bf16x8 a[2];
#pragma unroll
    for (int m = 0; m < 2; ++m) {
      if (rv[m]) {
        bf16x8 hv = *(const bf16x8*)(h1b + rowA[m] * 128 + k0);
#pragma unroll
        for (int jj = 0; jj < 4; ++jj) {
          a[m][jj]     = (__bf16)fmaxf(fmaf((float)hv[jj],     sc0[jj], sh0[jj]), 0.f);
          a[m][4 + jj] = (__bf16)fmaxf(fmaf((float)hv[4 + jj], sc1[jj], sh1[jj]), 0.f);
        }
      } else {
#pragma unroll
        for (int jj = 0; jj < 8; ++jj) a[m][jj] = (__bf16)0.f;
      }
    }
    bf16x8 bHi[4], bLo[4];
#pragma unroll
    for (int n = 0; n < 4; ++n) {
      int c = colw + n * 16 + l15;
      bHi[n] = *(const bf16x8*)(wtHi + c * 128 + k0);
      bLo[n] = *(const bf16x8*)(wtLo + c * 128 + k0);
    }
#pragma unroll
    for (int m = 0; m < 2; ++m)
#pragma unroll
      for (int n = 0; n < 4; ++n) {
        acc[m][n] = __builtin_amdgcn_mfma_f32_16x16x32_bf16(a[m], bHi[n], acc[m][n], 0, 0, 0);
        acc[m][n] = __builtin_amdgcn_mfma_f32_16x16x32_bf16(a[m], bLo[n], acc[m][n], 0, 0, 0);
      }
  }

#pragma unroll
  for (int n = 0; n < 4; ++n) {
    int c = colw + n * 16 + l15;
    float bv = bias[c];
#pragma unroll
    for (int m = 0; m < 2; ++m) {
      int rbase = row0 + m * 16 + lg * 4;
#pragma unroll
      for (int r = 0; r < 4; ++r) {
        int rr = rbase + r;
        if (rr < Nn) xbout[rr * 128 + c] = (__bf16)fmaxf(acc[m][n][r] + bv, 0.f);
      }
    }
  }
}

// ------------------------------ pooling (bf16 input) ------------------------
#define PCH 64
__global__ void k_pool(const __bf16* __restrict__ xb, const int* __restrict__ batch,
                       float* __restrict__ pooled, float* __restrict__ gcnt) {
  int wid = threadIdx.x >> 6, lane = threadIdx.x & 63;
  int w = blockIdx.x * 4 + wid;
  int n0 = w * PCH;
  if (n0 >= Nn) return;
  int n1 = (n0 + PCH < Nn) ? n0 + PCH : Nn;
  const unsigned int* x2 = (const unsigned int*)xb;
  float2 acc = make_float2(0.f, 0.f);
  int cur = batch[n0];
  int cnt = 0;
  for (int n = n0; n < n1; ++n) {
    int g = batch[n];                    // wave-uniform
    if (g != cur) {
      atomicAdd(&pooled[cur * 128 + lane * 2 + 0], acc.x);
      atomicAdd(&pooled[cur * 128 + lane * 2 + 1], acc.y);
      if (lane == 0) atomicAdd(&gcnt[cur], (float)cnt);
      acc = make_float2(0.f, 0.f); cnt = 0; cur = g;
    }
    unsigned int v = x2[n * 64 + lane];
    acc.x += __uint_as_float(v << 16);
    acc.y += __uint_as_float(v & 0xffff0000u);
    ++cnt;
  }
  atomicAdd(&pooled[cur * 128 + lane * 2 + 0], acc.x);
  atomicAdd(&pooled[cur * 128 + lane * 2 + 1], acc.y);
  if (lane == 0) atomicAdd(&gcnt[cur], (float)cnt);
}

__global__ void k_head(const float* __restrict__ pooled, const float* __restrict__ gcnt,
                       const float* __restrict__ Wc, const float* __restrict__ bc,
                       float* __restrict__ out) {
  __shared__ float p[128];
  int g = blockIdx.x, tid = threadIdx.x;
  p[tid] = pooled[g * 128 + tid] / fmaxf(gcnt[g], 1.0f);
  __syncthreads();
  if (tid < Cc) {
    float acc = bc[tid];
    for (int k = 0; k < 128; ++k) acc = fmaf(p[k], Wc[k * Cc + tid], acc);
    out[g * Cc + tid] = acc;
  }
}

// ------------------------------ launcher ------------------------------------
extern "C" void kernel_launch(void* const* d_in, const int* in_sizes, int n_in,
                              void* d_out, int out_size, void* d_ws, size_t ws_size,
                              hipStream_t stream) {
  const float* x    = (const float*)d_in[0];
  const float* ncn  = (const float*)d_in[1];
  const float* ecn  = (const float*)d_in[2];
  const float* W1   = (const float*)d_in[3];
  const float* b1   = (const float*)d_in[4];
  const float* g1   = (const float*)d_in[5];
  const float* be1  = (const float*)d_in[6];
  const float* W2   = (const float*)d_in[7];
  const float* b2   = (const float*)d_in[8];
  const float* Wc   = (const float*)d_in[9];
  const float* bc   = (const float*)d_in[10];
  const int*   ei   = (const int*)d_in[11];
  const int*   batch= (const int*)d_in[12];
  const int* src  = ei;
  const int* dstp = ei + Ee;

  float* fws = (float*)d_ws;
  float* partial  = fws;                       // 256*PPAD (1.6 MB)
  float* scaleA   = partial + 256 * PPAD;      // 128
  float* shiftA   = scaleA + 128;              // 128
  float* pooled   = shiftA + 128;              // G*128
  float* gcnt     = pooled + Gg * 128;         // 128
  int*   deg      = (int*)(gcnt + 128);        // N
  int*   offs     = deg + Nn;                  // N+64
  int*   cursor   = offs + Nn + 64;            // N
  int*   bsum     = cursor + Nn;               // 64
  int*   carry    = bsum + 64;                 // 64
  unsigned int* epk = (unsigned int*)(carry + 64); // E (4B packed edges)
  __bf16* wtHi    = (__bf16*)(epk + Ee);       // 6*16384 bf16
  __bf16* wtLo    = wtHi + 6 * 16384;          // 6*16384 bf16
  __bf16* xb      = wtLo + 6 * 16384;          // N*128 bf16 (12.8 MB)
  __bf16* h1b     = xb + Nn * 128;             // N*128 bf16

  // W prep + x cast + CSR build (once per call, reused by all 3 layers)
  k_wprep<<<48, 256, 0, stream>>>(W1, W2, wtHi, wtLo);
  k_xcast<<<2048, 256, 0, stream>>>(x, xb);
  hipMemsetAsync(deg, 0, Nn * sizeof(int), stream);
  k_deg<<<(Ee / 4 + 255) / 256, 256, 0, stream>>>(dstp, deg);
  k_scan1<<<NSCB, 1024, 0, stream>>>(deg, offs, bsum);
  k_scan2<<<1, 64, 0, stream>>>(bsum, carry);
  k_scan3<<<NSCB, 1024, 0, stream>>>(carry, offs, cursor);
  k_fill<<<(Ee / 4 + 255) / 256, 256, 0, stream>>>(src, dstp, ecn, cursor, epk);

  // fused layers: gemm1 does gather+residual+GEMM+BN-stats in one dispatch
  for (int l = 0; l < Ll; ++l) {
    k_gemm1<<<NBLK1, 256, 0, stream>>>(xb, ncn, offs, epk,
                                       wtHi + l * 16384, wtLo + l * 16384,
                                       b1 + l * 128, h1b, partial);
    k_bnfin<<<128, 256, 0, stream>>>(partial, g1 + l * 128, be1 + l * 128,
                                     scaleA, shiftA);
    k_gemm2<<<NBLK1, 256, 0, stream>>>(h1b, scaleA, shiftA,
                                       wtHi + (3 + l) * 16384, wtLo + (3 + l) * 16384,
                                       b2 + l * 128, xb);
  }

  hipMemsetAsync(pooled, 0, (Gg * 128 + 128) * sizeof(float), stream);
  k_pool<<<(Nn + PCH * 4 - 1) / (PCH * 4), 256, 0, stream>>>(xb, batch, pooled, gcnt);
  k_head<<<Gg, 128, 0, stream>>>(pooled, gcnt, Wc, bc, (float*)d_out);
}